// Round 1
// baseline (29787.814 us; speedup 1.0000x reference)
//
#include <hip/hip_runtime.h>
#include <cstdint>

// ---------------- configuration ----------------
#define HDIM 250          // hidden size
#define GDIM 1000         // 4*H gate rows
#define CH   64           // chunk length (steps) for inter-WG handoff
#define PP   4            // projection WGs per layer
#define HRING 4           // h ring depth (chunks)
#define XRING 4           // xw ring depth (chunks)
#define KV   27           // b128 weight chunks per row kept in VGPRs
#define KLD  5            // b128 weight chunks per row kept in LDS
#define KC   32           // total chunks (32*8 = 256 fp16 >= 250, zero padded)
#define RPAD 1024         // padded gate-row dimension
#define SMEM_BYTES 85504  // rec: 80K lds_w + 512 h + 2K fo + 1K red

typedef _Float16 f16x2 __attribute__((ext_vector_type(2)));

__device__ __forceinline__ float fdot2u(uint32_t w, uint32_t h, float acc) {
#if defined(__has_builtin) && __has_builtin(__builtin_amdgcn_fdot2)
  return __builtin_amdgcn_fdot2(__builtin_bit_cast(f16x2, w),
                                __builtin_bit_cast(f16x2, h), acc, false);
#else
  f16x2 wv = __builtin_bit_cast(f16x2, w), hv = __builtin_bit_cast(f16x2, h);
  return acc + (float)wv[0] * (float)hv[0] + (float)wv[1] * (float)hv[1];
#endif
}

__device__ __forceinline__ uint32_t pkh2(float a, float b) {
  f16x2 p; p[0] = (_Float16)a; p[1] = (_Float16)b;
  return __builtin_bit_cast(uint32_t, p);
}

// pack 8 consecutive f32 weights (zero beyond HDIM) into 4x fp16x2
__device__ __forceinline__ uint4 pack8(const float* row, int kq) {
  float c[8];
#pragma unroll
  for (int u = 0; u < 8; ++u) {
    int col = kq * 8 + u;
    c[u] = (col < HDIM) ? row[col] : 0.f;
  }
  uint4 r;
  r.x = pkh2(c[0], c[1]); r.y = pkh2(c[2], c[3]);
  r.z = pkh2(c[4], c[5]); r.w = pkh2(c[6], c[7]);
  return r;
}

__device__ __forceinline__ float sigm(float x) {
  return 1.f / (1.f + exp2f(-1.44269504088896341f * x));
}
__device__ __forceinline__ float tanh_(float x) {
  float e = exp2f(2.88539008177792681f * x);
  return 1.f - 2.f / (e + 1.f);
}

// ---------------- flags (in d_ws, zeroed each launch) ----------------
// F[0..1]   hCnt[li]       : h chunks produced for hRing[li] (li = producing rec layer 0/1)
// F[2..3]   xwConsumed[li] : xw chunks consumed by rec layer li+1
// F[4..11]  hDone[li][p]   : h chunks staged (consumed) by proj WG p of ring li
// F[16..271] xwReady[li][c]: per-chunk ready flag
#define F_HCNT(F, li)     (F)[(li)]
#define F_XWCON(F, li)    (F)[2 + (li)]
#define F_HDONE(F, li, p) (F)[4 + (li) * PP + (p)]
#define F_XWRDY(F, li, c) (F)[16 + (li) * 128 + (c)]

__device__ __forceinline__ int aload(int* p) {
  return __hip_atomic_load(p, __ATOMIC_RELAXED, __HIP_MEMORY_SCOPE_AGENT);
}
__device__ __forceinline__ void arel(int* p, int v) {
  __hip_atomic_store(p, v, __ATOMIC_RELEASE, __HIP_MEMORY_SCOPE_AGENT);
}
__device__ __forceinline__ void acq_fence() {
  __builtin_amdgcn_fence(__ATOMIC_ACQUIRE, "agent");
}
__device__ __forceinline__ void spin_ge(int* p, int tgt) {
  unsigned n = 0;
  while (aload(p) < tgt) {
    __builtin_amdgcn_s_sleep(2);
    if (++n > 200000000u) return;  // hang guard; result will fail visibly
  }
}

// ---------------- init: transpose Wih1/2 -> WT[li][j][RPAD], biases ----------------
__global__ void lstm_init(const float* __restrict__ Wih1, const float* __restrict__ bih1,
                          const float* __restrict__ bhh1, const float* __restrict__ Wih2,
                          const float* __restrict__ bih2, const float* __restrict__ bhh2,
                          float* __restrict__ WT, float* __restrict__ BV) {
  int idx = blockIdx.x * blockDim.x + threadIdx.x;
  int stride = gridDim.x * blockDim.x;
  for (int i = idx; i < 2 * HDIM * RPAD; i += stride) {
    int li = i / (HDIM * RPAD);
    int rem = i - li * HDIM * RPAD;
    int j = rem / RPAD, r = rem - j * RPAD;
    const float* W = li ? Wih2 : Wih1;
    WT[i] = (r < GDIM) ? W[r * HDIM + j] : 0.f;
  }
  for (int i = idx; i < 2 * RPAD; i += stride) {
    int li = i >> 10, r = i & 1023;
    const float* bi = li ? bih2 : bih1;
    const float* bh = li ? bhh2 : bhh1;
    BV[i] = (r < GDIM) ? bi[r] + bh[r] : 0.f;
  }
}

// ---------------- main persistent kernel ----------------
// blocks 0..2  : recurrent WGs (layers 0,1,2), Whh fp16-resident, per-step work local to CU
// blocks 3..10 : projection WGs: li = (bid-3)/PP selects layer li+1's input projection
__global__ __launch_bounds__(512, 2) void lstm_main(
    const float* __restrict__ x, const float* __restrict__ Wih0,
    const float* __restrict__ bih0, const float* __restrict__ bhh0,
    const float* __restrict__ Whh0, const float* __restrict__ Whh1,
    const float* __restrict__ Whh2, const float* __restrict__ Wl,
    const float* __restrict__ bl, int* __restrict__ F,
    const float* __restrict__ WT, const float* __restrict__ BV,
    float* __restrict__ hRing, float* __restrict__ xwRing,
    float* __restrict__ out, int T) {
  extern __shared__ char smem[];
  const int tid = threadIdx.x;
  const int bid = blockIdx.x;
  const int NC = T / CH;

  if (bid < 3) {
    // ================= recurrent role =================
    const int L = bid;
    uint4* lds_w = (uint4*)smem;                  // [KLD][2][512] b128 weight chunks
    uint32_t* lds_h = (uint32_t*)(smem + 81920);  // fp16 h[256] as 128 dwords
    float* lds_fo = (float*)(smem + 82432);       // f,o exchange [2][256]
    float* lds_red = (float*)(smem + 84480);      // final reduction [256]

    const float* Whh = (L == 0) ? Whh0 : (L == 1) ? Whh1 : Whh2;
    const int r0 = tid, r1 = tid + 500;  // gate rows owned by this thread
    uint4 wA[KV], wB[KV];
    float w00 = 0.f, w01 = 0.f, bb0 = 0.f, bb1 = 0.f, wl = 0.f;

    if (tid < 500) {
      const float* R0 = Whh + (size_t)r0 * HDIM;
      const float* R1 = Whh + (size_t)r1 * HDIM;
#pragma unroll
      for (int kq = 0; kq < KV; ++kq) { wA[kq] = pack8(R0, kq); wB[kq] = pack8(R1, kq); }
      for (int kq = KV; kq < KC; ++kq) {
        lds_w[((kq - KV) * 2 + 0) * 512 + tid] = pack8(R0, kq);
        lds_w[((kq - KV) * 2 + 1) * 512 + tid] = pack8(R1, kq);
      }
      if (L == 0) {
        w00 = Wih0[r0]; w01 = Wih0[r1];
        bb0 = bih0[r0] + bhh0[r0]; bb1 = bih0[r1] + bhh0[r1];
      }
    }
    if (tid < 128) lds_h[tid] = 0u;  // h(-1) = 0 (incl. zero padding 250..255)
    if (L == 2 && tid < HDIM) wl = Wl[tid];
    __syncthreads();

    const float* xwBase = xwRing + (size_t)(L > 0 ? L - 1 : 0) * XRING * CH * RPAD;
    float* hBase = hRing + (size_t)L * HRING * CH * HDIM;
    float c_st = 0.f, h_cur = 0.f;

    for (int tt = 0; tt < T; ++tt) {
      const int tc = tt & (CH - 1);
      const int c = tt >> 6;
      if (tc == 0) {  // chunk boundary: wait for inputs / ring backpressure
        if (tid == 0) {
          if (L > 0) spin_ge(&F_XWRDY(F, L - 1, c), 1);
          if (L < 2 && c >= HRING) {
            int cc = c - HRING;
            spin_ge(&F_HDONE(F, L, cc % PP), cc + 1);
          }
          acq_fence();
        }
        __syncthreads();
      }

      // per-step gate inputs (issued early, consumed after the dot)
      float xw0, xw1;
      if (L == 0) {
        float xt = x[tt];
        xw0 = fmaf(xt, w00, bb0); xw1 = fmaf(xt, w01, bb1);
      } else {
        const float* xp = xwBase + (size_t)(c & (XRING - 1)) * CH * RPAD + (size_t)tc * RPAD;
        xw0 = xp[r0]; xw1 = xp[r1];  // coalesced
      }

      // recurrent matvec: 2 rows x 250 via fp16 dot2, f32 accumulate
      float a0 = 0.f, b0 = 0.f, a1 = 0.f, b1 = 0.f;
#pragma unroll
      for (int kq = 0; kq < KC; ++kq) {
        uint4 hq = ((uint4*)lds_h)[kq];  // uniform broadcast read
        uint4 q0, q1;
        if (kq < KV) { q0 = wA[kq]; q1 = wB[kq]; }
        else {
          q0 = lds_w[((kq - KV) * 2 + 0) * 512 + tid];
          q1 = lds_w[((kq - KV) * 2 + 1) * 512 + tid];
        }
        a0 = fdot2u(q0.x, hq.x, a0); b0 = fdot2u(q0.y, hq.y, b0);
        a0 = fdot2u(q0.z, hq.z, a0); b0 = fdot2u(q0.w, hq.w, b0);
        a1 = fdot2u(q1.x, hq.x, a1); b1 = fdot2u(q1.y, hq.y, b1);
        a1 = fdot2u(q1.z, hq.z, a1); b1 = fdot2u(q1.w, hq.w, b1);
      }
      float g0 = a0 + b0 + xw0;
      float g1 = a1 + b1 + xw1;

      // activations: tid<250 holds (i,g); tid in [250,500) holds (f,o)
      float ii = 0.f, gg = 0.f;
      if (tid < HDIM) { ii = sigm(g0); gg = tanh_(g1); }
      else if (tid < 500) {
        int j = tid - HDIM;
        lds_fo[j] = sigm(g0); lds_fo[256 + j] = sigm(g1);
      }
      __syncthreads();
      if (tid < HDIM) {
        float ff = lds_fo[tid], oo = lds_fo[256 + tid];
        c_st = ff * c_st + ii * gg;
        h_cur = oo * tanh_(c_st);
        ((_Float16*)lds_h)[tid] = (_Float16)h_cur;  // h for next step (fp16)
        if (L < 2)
          hBase[(size_t)(c & (HRING - 1)) * CH * HDIM + (size_t)tc * HDIM + tid] = h_cur;
      }
      __syncthreads();

      if (tc == CH - 1 && tid == 0) {  // chunk end: publish
        if (L < 2) arel(&F_HCNT(F, L), c + 1);
        if (L > 0) arel(&F_XWCON(F, L - 1), c + 1);
      }
    }

    if (L == 2) {  // final linear on h2[T-1]
      if (tid < HDIM) lds_red[tid] = h_cur * wl;
      __syncthreads();
      if (tid == 0) {
        float s = bl[0];
        for (int j = 0; j < HDIM; ++j) s += lds_red[j];
        out[0] = s;
      }
    }
  } else {
    // ================= projection role =================
    const int li = (bid - 3) / PP;  // ring index: consumes hRing[li], feeds rec layer li+1
    const int p = (bid - 3) % PP;
    float* ldsH = (float*)smem;  // [64][257] f32, t-major, conflict-free stride
    const int lane = tid & 63, wid = tid >> 6;
    const float* WTl = WT + (size_t)li * HDIM * RPAD;
    const float* BVl = BV + (size_t)li * RPAD;

    for (int c = p; c < NC; c += PP) {
      if (tid == 0) {
        spin_ge(&F_HCNT(F, li), c + 1);
        if (c >= XRING) spin_ge(&F_XWCON(F, li), c - XRING + 1);
        acq_fence();
      }
      __syncthreads();
      // stage h chunk into LDS
      const float* hsrc = hRing + (size_t)li * HRING * CH * HDIM +
                          (size_t)(c & (HRING - 1)) * CH * HDIM;
      for (int t = wid; t < CH; t += 8)
        for (int j = lane; j < HDIM; j += 64)
          ldsH[t * 257 + j] = hsrc[t * HDIM + j];
      __syncthreads();
      if (tid == 0) arel(&F_HDONE(F, li, p), c + 1);  // slot may be recycled

      float* xdst = xwRing + (size_t)li * XRING * CH * RPAD +
                    (size_t)(c & (XRING - 1)) * CH * RPAD;
      const int rb0 = wid * 128;
      for (int grp = 0; grp < 16; ++grp) {
        const int rb = rb0 + grp * 8;
        float acc[8];
#pragma unroll
        for (int u = 0; u < 8; ++u) acc[u] = 0.f;
        const float* wp = WTl + rb;
        float4 wa = *(const float4*)(wp);
        float4 wb = *(const float4*)(wp + 4);
        for (int j = 0; j < HDIM; ++j) {
          int jn = (j + 1 < HDIM) ? j + 1 : HDIM - 1;
          float4 na = *(const float4*)(wp + (size_t)jn * RPAD);
          float4 nb = *(const float4*)(wp + (size_t)jn * RPAD + 4);
          float hj = ldsH[lane * 257 + j];
          acc[0] = fmaf(wa.x, hj, acc[0]); acc[1] = fmaf(wa.y, hj, acc[1]);
          acc[2] = fmaf(wa.z, hj, acc[2]); acc[3] = fmaf(wa.w, hj, acc[3]);
          acc[4] = fmaf(wb.x, hj, acc[4]); acc[5] = fmaf(wb.y, hj, acc[5]);
          acc[6] = fmaf(wb.z, hj, acc[6]); acc[7] = fmaf(wb.w, hj, acc[7]);
          wa = na; wb = nb;
        }
#pragma unroll
        for (int u = 0; u < 8; ++u) {
          int r = rb + u;
          if (r < GDIM) xdst[(size_t)lane * RPAD + r] = acc[u] + BVl[r];
        }
      }
      __syncthreads();
      if (tid == 0) arel(&F_XWRDY(F, li, c), 1);
    }
  }
}

// ---------------- launch ----------------
extern "C" void kernel_launch(void* const* d_in, const int* in_sizes, int n_in,
                              void* d_out, int out_size, void* d_ws, size_t ws_size,
                              hipStream_t stream) {
  const float* x    = (const float*)d_in[0];
  const float* Wih0 = (const float*)d_in[1];
  const float* Whh0 = (const float*)d_in[2];
  const float* bih0 = (const float*)d_in[3];
  const float* bhh0 = (const float*)d_in[4];
  const float* Wih1 = (const float*)d_in[5];
  const float* Whh1 = (const float*)d_in[6];
  const float* bih1 = (const float*)d_in[7];
  const float* bhh1 = (const float*)d_in[8];
  const float* Wih2 = (const float*)d_in[9];
  const float* Whh2 = (const float*)d_in[10];
  const float* bih2 = (const float*)d_in[11];
  const float* bhh2 = (const float*)d_in[12];
  const float* Wl   = (const float*)d_in[13];
  const float* bl   = (const float*)d_in[14];
  const int T = in_sizes[0];

  char* ws = (char*)d_ws;
  int*   F   = (int*)ws;                                        // 4096 B flags
  float* WT  = (float*)(ws + 4096);                             // 2,048,000 B
  float* BV  = (float*)(ws + 4096 + 2048000);                   // 8,192 B
  float* hR  = (float*)(ws + 4096 + 2048000 + 8192);            // 512,000 B
  float* xwR = (float*)(ws + 4096 + 2048000 + 8192 + 512000);   // 2,097,152 B

  hipMemsetAsync(F, 0, 4096, stream);  // reset protocol state every call/replay
  lstm_init<<<256, 256, 0, stream>>>(Wih1, bih1, bhh1, Wih2, bih2, bhh2, WT, BV);
  hipFuncSetAttribute(reinterpret_cast<const void*>(lstm_main),
                      hipFuncAttributeMaxDynamicSharedMemorySize, SMEM_BYTES);
  lstm_main<<<3 + 2 * PP, 512, SMEM_BYTES, stream>>>(
      x, Wih0, bih0, bhh0, Whh0, Whh1, Whh2, Wl, bl, F, WT, BV, hR, xwR,
      (float*)d_out, T);
}

// Round 2
// 21013.632 us; speedup vs baseline: 1.4175x; 1.4175x over previous
//
#include <hip/hip_runtime.h>
#include <cstdint>

// ---------------- configuration ----------------
#define HDIM 250          // hidden size
#define GDIM 1000         // 4*H gate rows
#define CH   64           // chunk length (steps) for inter-WG handoff
#define PP   4            // projection WGs per layer
#define HRING 4           // h ring depth (chunks)
#define XRING 4           // xw ring depth (chunks)
#define RPAD 1024         // padded gate-row dimension
#define NTH  512

// rec-role LDS layout: weights | h double-buffer (4 skewed segments) | reduce
#define W_LDS_QPT 18                        // LDS weight quads per thread
#define LDSW_BYTES (W_LDS_QPT * NTH * 16)   // 147456
#define HSEG 144                            // skewed segment stride (bank-offset +4/seg)
#define HBUF (4 * HSEG)                     // 576 B per h buffer
#define HB_BASE LDSW_BYTES                  // 147456
#define RED_BASE (HB_BASE + 2 * HBUF)       // 148608
#define SMEM_BYTES (RED_BASE + 1024)        // 149632  (proj role needs 65792)

typedef _Float16 f16x2 __attribute__((ext_vector_type(2)));

__device__ __forceinline__ float fdot2u(uint32_t w, uint32_t h, float acc) {
#if defined(__has_builtin) && __has_builtin(__builtin_amdgcn_fdot2)
  return __builtin_amdgcn_fdot2(__builtin_bit_cast(f16x2, w),
                                __builtin_bit_cast(f16x2, h), acc, false);
#else
  f16x2 wv = __builtin_bit_cast(f16x2, w), hv = __builtin_bit_cast(f16x2, h);
  return acc + (float)wv[0] * (float)hv[0] + (float)wv[1] * (float)hv[1];
#endif
}

__device__ __forceinline__ uint32_t pkh2(float a, float b) {
  f16x2 p; p[0] = (_Float16)a; p[1] = (_Float16)b;
  return __builtin_bit_cast(uint32_t, p);
}

// pack 8 consecutive f32 weights (zero beyond HDIM / null row) into 4x fp16x2
__device__ __forceinline__ uint4 pack8q(const float* rp, int c0) {
  float c[8];
#pragma unroll
  for (int u = 0; u < 8; ++u) {
    int col = c0 + u;
    c[u] = (rp && col < HDIM) ? rp[col] : 0.f;
  }
  uint4 r;
  r.x = pkh2(c[0], c[1]); r.y = pkh2(c[2], c[3]);
  r.z = pkh2(c[4], c[5]); r.w = pkh2(c[6], c[7]);
  return r;
}

__device__ __forceinline__ float sigm(float x) {
  return 1.f / (1.f + exp2f(-1.44269504088896341f * x));
}
__device__ __forceinline__ float tanh_(float x) {
  float e = exp2f(2.88539008177792681f * x);
  return 1.f - 2.f / (e + 1.f);
}

// DPP quad_perm: 0xB1 = lane^1, 0x4E = lane^2 (within 4-lane quads)
template <int CTRL>
__device__ __forceinline__ float dppq(float v) {
  return __builtin_bit_cast(
      float, __builtin_amdgcn_update_dpp(0, __builtin_bit_cast(int, v), CTRL,
                                         0xF, 0xF, true));
}

// per-row chunk split: rows 0-5 -> 6 VGPR + 2 LDS quads; rows 6-7 -> 5 + 3
__device__ __forceinline__ constexpr int kv_count(int r) { return r < 6 ? 6 : 5; }
__device__ __forceinline__ constexpr int wv_idx(int r, int k) {
  return r < 6 ? r * 6 + k : 36 + (r - 6) * 5 + k;
}
__device__ __forceinline__ constexpr int wl_idx(int r, int k) {
  return r < 6 ? r * 2 + (k - 6) : 12 + (r - 6) * 3 + (k - 5);
}

// lgkmcnt-only barrier: keeps global (VMEM) prefetches in flight across steps
__device__ __forceinline__ void step_barrier() {
  asm volatile("s_waitcnt lgkmcnt(0)\n\ts_barrier" ::: "memory");
}

// ---------------- flags (in d_ws, zeroed each launch) ----------------
#define F_HCNT(F, li)     (F)[(li)]
#define F_XWCON(F, li)    (F)[2 + (li)]
#define F_HDONE(F, li, p) (F)[4 + (li) * PP + (p)]
#define F_XWRDY(F, li, c) (F)[16 + (li) * 128 + (c)]

__device__ __forceinline__ int aload(int* p) {
  return __hip_atomic_load(p, __ATOMIC_RELAXED, __HIP_MEMORY_SCOPE_AGENT);
}
__device__ __forceinline__ void arel(int* p, int v) {
  __hip_atomic_store(p, v, __ATOMIC_RELEASE, __HIP_MEMORY_SCOPE_AGENT);
}
__device__ __forceinline__ void acq_fence() {
  __builtin_amdgcn_fence(__ATOMIC_ACQUIRE, "agent");
}
__device__ __forceinline__ void spin_ge(int* p, int tgt) {
  unsigned n = 0;
  while (aload(p) < tgt) {
    __builtin_amdgcn_s_sleep(2);
    if (++n > 200000000u) return;  // hang guard; result will fail visibly
  }
}

// ---------------- init: transpose Wih1/2 -> WT[li][j][RPAD], biases ----------------
__global__ void lstm_init(const float* __restrict__ Wih1, const float* __restrict__ bih1,
                          const float* __restrict__ bhh1, const float* __restrict__ Wih2,
                          const float* __restrict__ bih2, const float* __restrict__ bhh2,
                          float* __restrict__ WT, float* __restrict__ BV) {
  int idx = blockIdx.x * blockDim.x + threadIdx.x;
  int stride = gridDim.x * blockDim.x;
  for (int i = idx; i < 2 * HDIM * RPAD; i += stride) {
    int li = i / (HDIM * RPAD);
    int rem = i - li * HDIM * RPAD;
    int j = rem / RPAD, r = rem - j * RPAD;
    const float* W = li ? Wih2 : Wih1;
    WT[i] = (r < GDIM) ? W[r * HDIM + j] : 0.f;
  }
  for (int i = idx; i < 2 * RPAD; i += stride) {
    int li = i >> 10, r = i & 1023;
    const float* bi = li ? bih2 : bih1;
    const float* bh = li ? bhh2 : bhh1;
    BV[i] = (r < GDIM) ? bi[r] + bh[r] : 0.f;
  }
}

// ---------------- main persistent kernel ----------------
// blocks 0..2  : recurrent WGs (layers 0,1,2). 128 groups x 4 lanes; group owns
//                2 hidden units x 4 gates (8 rows); lane slice = 64 columns.
//                Weights: 46 quads VGPR + 18 quads LDS per thread (no spill).
// blocks 3..10 : projection WGs (unchanged from R1).
__global__ __launch_bounds__(512, 2) void lstm_main(
    const float* __restrict__ x, const float* __restrict__ Wih0,
    const float* __restrict__ bih0, const float* __restrict__ bhh0,
    const float* __restrict__ Whh0, const float* __restrict__ Whh1,
    const float* __restrict__ Whh2, const float* __restrict__ Wl,
    const float* __restrict__ bl, int* __restrict__ F,
    const float* __restrict__ WT, const float* __restrict__ BV,
    float* __restrict__ hRing, float* __restrict__ xwRing,
    float* __restrict__ out, int T) {
  extern __shared__ char smem[];
  const int tid = threadIdx.x;
  const int bid = blockIdx.x;
  const int NC = T / CH;

  if (bid < 3) {
    // ================= recurrent role =================
    const int L = bid;
    const int grp = tid >> 2, sl = tid & 3;
    const bool lead = (sl < 2);
    const int uu = 2 * grp + sl;  // unit owned when lead (sl<2)

    const float* Whh = (L == 0) ? Whh0 : (L == 1) ? Whh1 : Whh2;
    uint4 wv[46];
    {
#pragma unroll
      for (int r = 0; r < 8; ++r) {
        const int w = r >> 2, gate = r & 3;
        const int u = 2 * grp + w;
        const float* rp = (u < HDIM) ? (Whh + (size_t)(gate * HDIM + u) * HDIM) : nullptr;
#pragma unroll
        for (int k = 0; k < 8; ++k) {
          uint4 q = pack8q(rp, sl * 64 + k * 8);
          if (k < kv_count(r)) wv[wv_idx(r, k)] = q;
          else *(uint4*)(smem + (size_t)(wl_idx(r, k) * NTH + tid) * 16) = q;
        }
      }
    }
    // zero both h buffers (avoid NaN garbage in padded entries 250..255)
    for (int i = tid; i < (2 * HBUF) / 4; i += NTH)
      *(uint32_t*)(smem + HB_BASE + 4 * i) = 0u;
    __syncthreads();

    const float* xwBase = xwRing + (size_t)(L > 0 ? L - 1 : 0) * XRING * CH * RPAD;
    float* hBase = hRing + (size_t)L * HRING * CH * HDIM;
    float c_st = 0.f, h_last = 0.f;

    for (int tt = 0; tt < T; ++tt) {
      const int tc = tt & (CH - 1);
      const int c = tt >> 6;
      if (tc == 0) {  // chunk boundary: wait for inputs / ring backpressure
        if (tid == 0) {
          if (L > 0) spin_ge(&F_XWRDY(F, L - 1, c), 1);
          if (L < 2 && c >= HRING) {
            int cc = c - HRING;
            spin_ge(&F_HDONE(F, L, cc % PP), cc + 1);
          }
          acq_fence();
        }
        __syncthreads();
      }

      // gate inputs for this step (issued before barrier; VMEM rides across it)
      float xw0 = 0.f, xw1 = 0.f, xw2 = 0.f, xw3 = 0.f;
      if (lead && uu < HDIM) {
        if (L == 0) {
          float xt = x[tt];
          xw0 = fmaf(xt, Wih0[uu], bih0[uu] + bhh0[uu]);
          xw1 = fmaf(xt, Wih0[250 + uu], bih0[250 + uu] + bhh0[250 + uu]);
          xw2 = fmaf(xt, Wih0[500 + uu], bih0[500 + uu] + bhh0[500 + uu]);
          xw3 = fmaf(xt, Wih0[750 + uu], bih0[750 + uu] + bhh0[750 + uu]);
        } else {
          const float* xp = xwBase + (size_t)(c & (XRING - 1)) * CH * RPAD +
                            (size_t)tc * RPAD;
          xw0 = xp[uu]; xw1 = xp[250 + uu]; xw2 = xp[500 + uu]; xw3 = xp[750 + uu];
        }
      }

      step_barrier();  // h(p) writes from previous step now visible (lgkm only)

      // dot: 8 rows x 64 cols, fp16 dot2, f32 accumulate
      const char* hb = smem + HB_BASE + (tt & 1) * HBUF + sl * HSEG;
      float acc[8] = {0.f, 0.f, 0.f, 0.f, 0.f, 0.f, 0.f, 0.f};
#pragma unroll
      for (int k = 0; k < 8; ++k) {
        const uint4 hq = *(const uint4*)(hb + k * 16);
#pragma unroll
        for (int r = 0; r < 8; ++r) {
          uint4 wq = (k < kv_count(r))
                         ? wv[wv_idx(r, k)]
                         : *(const uint4*)(smem + (size_t)(wl_idx(r, k) * NTH + tid) * 16);
          acc[r] = fdot2u(wq.x, hq.x, acc[r]);
          acc[r] = fdot2u(wq.y, hq.y, acc[r]);
          acc[r] = fdot2u(wq.z, hq.z, acc[r]);
          acc[r] = fdot2u(wq.w, hq.w, acc[r]);
        }
      }
      // butterfly across the 4 slice lanes (DPP, VALU pipe)
#pragma unroll
      for (int r = 0; r < 8; ++r) {
        acc[r] += dppq<0xB1>(acc[r]);
        acc[r] += dppq<0x4E>(acc[r]);
      }

      // finalize: lanes 0,1 of each quad own one unit each
      if (lead) {
        const int of = sl * 4;
        float gi = acc[of + 0] + xw0, gf = acc[of + 1] + xw1;
        float gG = acc[of + 2] + xw2, go = acc[of + 3] + xw3;
        float ii = sigm(gi), ff = sigm(gf), tg = tanh_(gG), oo = sigm(go);
        c_st = ff * c_st + ii * tg;
        float hn = oo * tanh_(c_st);
        h_last = hn;
        float hOther = dppq<0xB1>(hn);  // lane0 <- lane1's h (both active here)
        if (sl == 0) {
          // fp16 pair into next-step h buffer (skewed segment, b32 write)
          char* hw = smem + HB_BASE + ((tt + 1) & 1) * HBUF + (uu >> 6) * HSEG +
                     (uu & 63) * 2;
          *(uint32_t*)hw = pkh2(hn, hOther);
          if (L < 2 && uu < HDIM) {
            float2 hp; hp.x = hn; hp.y = hOther;
            *(float2*)(hBase + (size_t)(c & (HRING - 1)) * CH * HDIM +
                       (size_t)tc * HDIM + uu) = hp;
          }
        }
      }

      if (tc == CH - 1) {  // chunk end: full barrier (drains vmcnt) then publish
        __syncthreads();
        if (tid == 0) {
          if (L < 2) arel(&F_HCNT(F, L), c + 1);
          if (L > 0) arel(&F_XWCON(F, L - 1), c + 1);
        }
      }
    }

    if (L == 2) {  // final linear on h2[T-1]
      float* red = (float*)(smem + RED_BASE);
      if (lead && uu < HDIM) red[uu] = h_last;
      __syncthreads();
      if (tid == 0) {
        float s = bl[0];
        for (int j = 0; j < HDIM; ++j) s += red[j] * Wl[j];
        out[0] = s;
      }
    }
  } else {
    // ================= projection role (unchanged from R1) =================
    const int li = (bid - 3) / PP;
    const int p = (bid - 3) % PP;
    float* ldsH = (float*)smem;  // [64][257] f32
    const int lane = tid & 63, wid = tid >> 6;
    const float* WTl = WT + (size_t)li * HDIM * RPAD;
    const float* BVl = BV + (size_t)li * RPAD;

    for (int c = p; c < NC; c += PP) {
      if (tid == 0) {
        spin_ge(&F_HCNT(F, li), c + 1);
        if (c >= XRING) spin_ge(&F_XWCON(F, li), c - XRING + 1);
        acq_fence();
      }
      __syncthreads();
      const float* hsrc = hRing + (size_t)li * HRING * CH * HDIM +
                          (size_t)(c & (HRING - 1)) * CH * HDIM;
      for (int t = wid; t < CH; t += 8)
        for (int j = lane; j < HDIM; j += 64)
          ldsH[t * 257 + j] = hsrc[t * HDIM + j];
      __syncthreads();
      if (tid == 0) arel(&F_HDONE(F, li, p), c + 1);

      float* xdst = xwRing + (size_t)li * XRING * CH * RPAD +
                    (size_t)(c & (XRING - 1)) * CH * RPAD;
      const int rb0 = wid * 128;
      for (int grpq = 0; grpq < 16; ++grpq) {
        const int rb = rb0 + grpq * 8;
        float acc[8];
#pragma unroll
        for (int u = 0; u < 8; ++u) acc[u] = 0.f;
        const float* wp = WTl + rb;
        float4 wa = *(const float4*)(wp);
        float4 wb = *(const float4*)(wp + 4);
        for (int j = 0; j < HDIM; ++j) {
          int jn = (j + 1 < HDIM) ? j + 1 : HDIM - 1;
          float4 na = *(const float4*)(wp + (size_t)jn * RPAD);
          float4 nb = *(const float4*)(wp + (size_t)jn * RPAD + 4);
          float hj = ldsH[lane * 257 + j];
          acc[0] = fmaf(wa.x, hj, acc[0]); acc[1] = fmaf(wa.y, hj, acc[1]);
          acc[2] = fmaf(wa.z, hj, acc[2]); acc[3] = fmaf(wa.w, hj, acc[3]);
          acc[4] = fmaf(wb.x, hj, acc[4]); acc[5] = fmaf(wb.y, hj, acc[5]);
          acc[6] = fmaf(wb.z, hj, acc[6]); acc[7] = fmaf(wb.w, hj, acc[7]);
          wa = na; wb = nb;
        }
#pragma unroll
        for (int u = 0; u < 8; ++u) {
          int r = rb + u;
          if (r < GDIM) xdst[(size_t)lane * RPAD + r] = acc[u] + BVl[r];
        }
      }
      __syncthreads();
      if (tid == 0) arel(&F_XWRDY(F, li, c), 1);
    }
  }
}

// ---------------- launch ----------------
extern "C" void kernel_launch(void* const* d_in, const int* in_sizes, int n_in,
                              void* d_out, int out_size, void* d_ws, size_t ws_size,
                              hipStream_t stream) {
  const float* x    = (const float*)d_in[0];
  const float* Wih0 = (const float*)d_in[1];
  const float* Whh0 = (const float*)d_in[2];
  const float* bih0 = (const float*)d_in[3];
  const float* bhh0 = (const float*)d_in[4];
  const float* Wih1 = (const float*)d_in[5];
  const float* Whh1 = (const float*)d_in[6];
  const float* bih1 = (const float*)d_in[7];
  const float* bhh1 = (const float*)d_in[8];
  const float* Wih2 = (const float*)d_in[9];
  const float* Whh2 = (const float*)d_in[10];
  const float* bih2 = (const float*)d_in[11];
  const float* bhh2 = (const float*)d_in[12];
  const float* Wl   = (const float*)d_in[13];
  const float* bl   = (const float*)d_in[14];
  const int T = in_sizes[0];

  char* ws = (char*)d_ws;
  int*   F   = (int*)ws;                                        // 4096 B flags
  float* WT  = (float*)(ws + 4096);                             // 2,048,000 B
  float* BV  = (float*)(ws + 4096 + 2048000);                   // 8,192 B
  float* hR  = (float*)(ws + 4096 + 2048000 + 8192);            // 512,000 B
  float* xwR = (float*)(ws + 4096 + 2048000 + 8192 + 512000);   // 2,097,152 B

  hipMemsetAsync(F, 0, 4096, stream);  // reset protocol state every call/replay
  lstm_init<<<256, 256, 0, stream>>>(Wih1, bih1, bhh1, Wih2, bih2, bhh2, WT, BV);
  hipFuncSetAttribute(reinterpret_cast<const void*>(lstm_main),
                      hipFuncAttributeMaxDynamicSharedMemorySize, SMEM_BYTES);
  lstm_main<<<3 + 2 * PP, 512, SMEM_BYTES, stream>>>(
      x, Wih0, bih0, bhh0, Whh0, Whh1, Whh2, Wl, bl, F, WT, BV, hR, xwR,
      (float*)d_out, T);
}

// Round 3
// 21011.780 us; speedup vs baseline: 1.4177x; 1.0001x over previous
//
#include <hip/hip_runtime.h>
#include <cstdint>

// ---------------- configuration ----------------
#define HDIM 250          // hidden size
#define GDIM 1000         // 4*H gate rows
#define CH   64           // chunk length (steps) for inter-WG handoff
#define PP   4            // projection WGs per layer
#define HRING 4           // h ring depth (chunks)
#define XRING 4           // xw ring depth (chunks)
#define RPAD 1024         // padded gate-row dimension
#define NTH  512

// rec-role LDS layout: weights | h double-buffer (4 skewed segments) | reduce
#define W_LDS_QPT 19                        // LDS weight quads per thread
#define LDSW_BYTES (W_LDS_QPT * NTH * 16)   // 155648
#define HSEG 144                            // skewed segment stride (bank-offset +4/seg)
#define HBUF (4 * HSEG)                     // 576 B per h buffer
#define HB_BASE LDSW_BYTES                  // 155648
#define RED_BASE (HB_BASE + 2 * HBUF)       // 156800
#define SMEM_BYTES (RED_BASE + 1024)        // 157824 <= 163840 (160 KiB)

typedef _Float16 f16x2 __attribute__((ext_vector_type(2)));

__device__ __forceinline__ float fdot2u(uint32_t w, uint32_t h, float acc) {
#if defined(__has_builtin) && __has_builtin(__builtin_amdgcn_fdot2)
  return __builtin_amdgcn_fdot2(__builtin_bit_cast(f16x2, w),
                                __builtin_bit_cast(f16x2, h), acc, false);
#else
  f16x2 wv = __builtin_bit_cast(f16x2, w), hv = __builtin_bit_cast(f16x2, h);
  return acc + (float)wv[0] * (float)hv[0] + (float)wv[1] * (float)hv[1];
#endif
}

__device__ __forceinline__ uint32_t pkh2(float a, float b) {
  f16x2 p; p[0] = (_Float16)a; p[1] = (_Float16)b;
  return __builtin_bit_cast(uint32_t, p);
}

// pack 8 consecutive f32 weights (zero beyond HDIM / null row) into 4x fp16x2
__device__ __forceinline__ uint4 pack8q(const float* rp, int c0) {
  float c[8];
#pragma unroll
  for (int u = 0; u < 8; ++u) {
    int col = c0 + u;
    c[u] = (rp && col < HDIM) ? rp[col] : 0.f;
  }
  uint4 r;
  r.x = pkh2(c[0], c[1]); r.y = pkh2(c[2], c[3]);
  r.z = pkh2(c[4], c[5]); r.w = pkh2(c[6], c[7]);
  return r;
}

__device__ __forceinline__ float sigm(float x) {
  return 1.f / (1.f + exp2f(-1.44269504088896341f * x));
}
__device__ __forceinline__ float tanh_(float x) {
  float e = exp2f(2.88539008177792681f * x);
  return 1.f - 2.f / (e + 1.f);
}

// DPP quad_perm: 0xB1 = lane^1, 0x4E = lane^2 (within 4-lane quads)
template <int CTRL>
__device__ __forceinline__ float dppq(float v) {
  return __builtin_bit_cast(
      float, __builtin_amdgcn_update_dpp(0, __builtin_bit_cast(int, v), CTRL,
                                         0xF, 0xF, true));
}

// per-row chunk split: rows 0-4 -> 6 VGPR + 2 LDS quads; rows 5-7 -> 5 + 3
// total: 45 VGPR quads (180 regs), 19 LDS quads
__device__ __forceinline__ constexpr int kv_count(int r) { return r < 5 ? 6 : 5; }
__device__ __forceinline__ constexpr int wv_idx(int r, int k) {
  return r < 5 ? r * 6 + k : 30 + (r - 5) * 5 + k;
}
__device__ __forceinline__ constexpr int wl_idx(int r, int k) {
  return r < 5 ? r * 2 + (k - 6) : 10 + (r - 5) * 3 + (k - 5);
}

// lgkmcnt-only barrier: keeps global (VMEM) prefetches in flight across steps
__device__ __forceinline__ void step_barrier() {
  asm volatile("s_waitcnt lgkmcnt(0)\n\ts_barrier" ::: "memory");
}

// ---------------- flags (in d_ws, zeroed each launch) ----------------
#define F_HCNT(F, li)     (F)[(li)]
#define F_XWCON(F, li)    (F)[2 + (li)]
#define F_HDONE(F, li, p) (F)[4 + (li) * PP + (p)]
#define F_XWRDY(F, li, c) (F)[16 + (li) * 128 + (c)]

__device__ __forceinline__ int aload(int* p) {
  return __hip_atomic_load(p, __ATOMIC_RELAXED, __HIP_MEMORY_SCOPE_AGENT);
}
__device__ __forceinline__ void arel(int* p, int v) {
  __hip_atomic_store(p, v, __ATOMIC_RELEASE, __HIP_MEMORY_SCOPE_AGENT);
}
__device__ __forceinline__ void acq_fence() {
  __builtin_amdgcn_fence(__ATOMIC_ACQUIRE, "agent");
}
__device__ __forceinline__ void spin_ge(int* p, int tgt) {
  unsigned n = 0;
  while (aload(p) < tgt) {
    __builtin_amdgcn_s_sleep(2);
    if (++n > 200000000u) return;  // hang guard; result will fail visibly
  }
}

// ---------------- init: transpose Wih1/2 -> WT[li][j][RPAD], biases ----------------
__global__ void lstm_init(const float* __restrict__ Wih1, const float* __restrict__ bih1,
                          const float* __restrict__ bhh1, const float* __restrict__ Wih2,
                          const float* __restrict__ bih2, const float* __restrict__ bhh2,
                          float* __restrict__ WT, float* __restrict__ BV) {
  int idx = blockIdx.x * blockDim.x + threadIdx.x;
  int stride = gridDim.x * blockDim.x;
  for (int i = idx; i < 2 * HDIM * RPAD; i += stride) {
    int li = i / (HDIM * RPAD);
    int rem = i - li * HDIM * RPAD;
    int j = rem / RPAD, r = rem - j * RPAD;
    const float* W = li ? Wih2 : Wih1;
    WT[i] = (r < GDIM) ? W[r * HDIM + j] : 0.f;
  }
  for (int i = idx; i < 2 * RPAD; i += stride) {
    int li = i >> 10, r = i & 1023;
    const float* bi = li ? bih2 : bih1;
    const float* bh = li ? bhh2 : bhh1;
    BV[i] = (r < GDIM) ? bi[r] + bh[r] : 0.f;
  }
}

// ---------------- main persistent kernel ----------------
// blocks 0..2  : recurrent WGs (layers 0,1,2). 128 groups x 4 lanes; group owns
//                2 hidden units x 4 gates (8 rows); lane slice = 64 columns.
//                Weights: 45 quads VGPR + 19 quads LDS per thread (no spill at
//                a 256-reg budget, pinned via amdgpu_waves_per_eu(2,2)).
// blocks 3..10 : projection WGs.
__global__ void __launch_bounds__(512)
__attribute__((amdgpu_waves_per_eu(2, 2))) lstm_main(
    const float* __restrict__ x, const float* __restrict__ Wih0,
    const float* __restrict__ bih0, const float* __restrict__ bhh0,
    const float* __restrict__ Whh0, const float* __restrict__ Whh1,
    const float* __restrict__ Whh2, const float* __restrict__ Wl,
    const float* __restrict__ bl, int* __restrict__ F,
    const float* __restrict__ WT, const float* __restrict__ BV,
    float* __restrict__ hRing, float* __restrict__ xwRing,
    float* __restrict__ out, int T) {
  extern __shared__ char smem[];
  const int tid = threadIdx.x;
  const int bid = blockIdx.x;
  const int NC = T / CH;

  if (bid < 3) {
    // ================= recurrent role =================
    const int L = bid;
    const int grp = tid >> 2, sl = tid & 3;
    const bool lead = (sl < 2);
    const int uu = 2 * grp + sl;  // unit owned when lead (sl<2)

    const float* Whh = (L == 0) ? Whh0 : (L == 1) ? Whh1 : Whh2;
    uint4 wv[45];
    {
#pragma unroll
      for (int r = 0; r < 8; ++r) {
        const int w = r >> 2, gate = r & 3;
        const int u = 2 * grp + w;
        const float* rp = (u < HDIM) ? (Whh + (size_t)(gate * HDIM + u) * HDIM) : nullptr;
#pragma unroll
        for (int k = 0; k < 8; ++k) {
          uint4 q = pack8q(rp, sl * 64 + k * 8);
          if (k < kv_count(r)) wv[wv_idx(r, k)] = q;
          else *(uint4*)(smem + (size_t)(wl_idx(r, k) * NTH + tid) * 16) = q;
        }
      }
    }
    // zero both h buffers (avoid NaN garbage in padded entries 250..255)
    for (int i = tid; i < (2 * HBUF) / 4; i += NTH)
      *(uint32_t*)(smem + HB_BASE + 4 * i) = 0u;
    __syncthreads();

    const float* xwBase = xwRing + (size_t)(L > 0 ? L - 1 : 0) * XRING * CH * RPAD;
    float* hBase = hRing + (size_t)L * HRING * CH * HDIM;
    float c_st = 0.f, h_last = 0.f;

    for (int tt = 0; tt < T; ++tt) {
      const int tc = tt & (CH - 1);
      const int c = tt >> 6;
      if (tc == 0) {  // chunk boundary: wait for inputs / ring backpressure
        if (tid == 0) {
          if (L > 0) spin_ge(&F_XWRDY(F, L - 1, c), 1);
          if (L < 2 && c >= HRING) {
            int cc = c - HRING;
            spin_ge(&F_HDONE(F, L, cc % PP), cc + 1);
          }
          acq_fence();
        }
        __syncthreads();
      }

      // gate inputs for this step (issued before barrier; VMEM rides across it)
      float xw0 = 0.f, xw1 = 0.f, xw2 = 0.f, xw3 = 0.f;
      if (lead && uu < HDIM) {
        if (L == 0) {
          float xt = x[tt];
          xw0 = fmaf(xt, Wih0[uu], bih0[uu] + bhh0[uu]);
          xw1 = fmaf(xt, Wih0[250 + uu], bih0[250 + uu] + bhh0[250 + uu]);
          xw2 = fmaf(xt, Wih0[500 + uu], bih0[500 + uu] + bhh0[500 + uu]);
          xw3 = fmaf(xt, Wih0[750 + uu], bih0[750 + uu] + bhh0[750 + uu]);
        } else {
          const float* xp = xwBase + (size_t)(c & (XRING - 1)) * CH * RPAD +
                            (size_t)tc * RPAD;
          xw0 = xp[uu]; xw1 = xp[250 + uu]; xw2 = xp[500 + uu]; xw3 = xp[750 + uu];
        }
      }

      step_barrier();  // h(p) writes from previous step now visible (lgkm only)

      // dot: 8 rows x 64 cols, fp16 dot2, f32 accumulate
      const char* hb = smem + HB_BASE + (tt & 1) * HBUF + sl * HSEG;
      float acc[8] = {0.f, 0.f, 0.f, 0.f, 0.f, 0.f, 0.f, 0.f};
#pragma unroll
      for (int k = 0; k < 8; ++k) {
        const uint4 hq = *(const uint4*)(hb + k * 16);
#pragma unroll
        for (int r = 0; r < 8; ++r) {
          uint4 wq = (k < kv_count(r))
                         ? wv[wv_idx(r, k)]
                         : *(const uint4*)(smem + (size_t)(wl_idx(r, k) * NTH + tid) * 16);
          acc[r] = fdot2u(wq.x, hq.x, acc[r]);
          acc[r] = fdot2u(wq.y, hq.y, acc[r]);
          acc[r] = fdot2u(wq.z, hq.z, acc[r]);
          acc[r] = fdot2u(wq.w, hq.w, acc[r]);
        }
      }
      // butterfly across the 4 slice lanes (DPP, VALU pipe)
#pragma unroll
      for (int r = 0; r < 8; ++r) {
        acc[r] += dppq<0xB1>(acc[r]);
        acc[r] += dppq<0x4E>(acc[r]);
      }

      // finalize: lanes 0,1 of each quad own one unit each
      if (lead) {
        const int of = sl * 4;
        float gi = acc[of + 0] + xw0, gf = acc[of + 1] + xw1;
        float gG = acc[of + 2] + xw2, go = acc[of + 3] + xw3;
        float ii = sigm(gi), ff = sigm(gf), tg = tanh_(gG), oo = sigm(go);
        c_st = ff * c_st + ii * tg;
        float hn = oo * tanh_(c_st);
        h_last = hn;
        float hOther = dppq<0xB1>(hn);  // lane0 <- lane1's h (both active here)
        if (sl == 0) {
          // fp16 pair into next-step h buffer (skewed segment, b32 write)
          char* hw = smem + HB_BASE + ((tt + 1) & 1) * HBUF + (uu >> 6) * HSEG +
                     (uu & 63) * 2;
          *(uint32_t*)hw = pkh2(hn, hOther);
          if (L < 2 && uu < HDIM) {
            float2 hp; hp.x = hn; hp.y = hOther;
            *(float2*)(hBase + (size_t)(c & (HRING - 1)) * CH * HDIM +
                       (size_t)tc * HDIM + uu) = hp;
          }
        }
      }

      if (tc == CH - 1) {  // chunk end: full barrier (drains vmcnt) then publish
        __syncthreads();
        if (tid == 0) {
          if (L < 2) arel(&F_HCNT(F, L), c + 1);
          if (L > 0) arel(&F_XWCON(F, L - 1), c + 1);
        }
      }
    }

    if (L == 2) {  // final linear on h2[T-1]
      float* red = (float*)(smem + RED_BASE);
      if (lead && uu < HDIM) red[uu] = h_last;
      __syncthreads();
      if (tid == 0) {
        float s = bl[0];
        for (int j = 0; j < HDIM; ++j) s += red[j] * Wl[j];
        out[0] = s;
      }
    }
  } else {
    // ================= projection role =================
    const int li = (bid - 3) / PP;
    const int p = (bid - 3) % PP;
    float* ldsH = (float*)smem;  // [64][257] f32
    const int lane = tid & 63, wid = tid >> 6;
    const float* WTl = WT + (size_t)li * HDIM * RPAD;
    const float* BVl = BV + (size_t)li * RPAD;

    for (int c = p; c < NC; c += PP) {
      if (tid == 0) {
        spin_ge(&F_HCNT(F, li), c + 1);
        if (c >= XRING) spin_ge(&F_XWCON(F, li), c - XRING + 1);
        acq_fence();
      }
      __syncthreads();
      const float* hsrc = hRing + (size_t)li * HRING * CH * HDIM +
                          (size_t)(c & (HRING - 1)) * CH * HDIM;
      for (int t = wid; t < CH; t += 8)
        for (int j = lane; j < HDIM; j += 64)
          ldsH[t * 257 + j] = hsrc[t * HDIM + j];
      __syncthreads();
      if (tid == 0) arel(&F_HDONE(F, li, p), c + 1);

      float* xdst = xwRing + (size_t)li * XRING * CH * RPAD +
                    (size_t)(c & (XRING - 1)) * CH * RPAD;
      const int rb0 = wid * 128;
      for (int grpq = 0; grpq < 16; ++grpq) {
        const int rb = rb0 + grpq * 8;
        float acc[8];
#pragma unroll
        for (int u = 0; u < 8; ++u) acc[u] = 0.f;
        const float* wp = WTl + rb;
        float4 wa = *(const float4*)(wp);
        float4 wb = *(const float4*)(wp + 4);
        for (int j = 0; j < HDIM; ++j) {
          int jn = (j + 1 < HDIM) ? j + 1 : HDIM - 1;
          float4 na = *(const float4*)(wp + (size_t)jn * RPAD);
          float4 nb = *(const float4*)(wp + (size_t)jn * RPAD + 4);
          float hj = ldsH[lane * 257 + j];
          acc[0] = fmaf(wa.x, hj, acc[0]); acc[1] = fmaf(wa.y, hj, acc[1]);
          acc[2] = fmaf(wa.z, hj, acc[2]); acc[3] = fmaf(wa.w, hj, acc[3]);
          acc[4] = fmaf(wb.x, hj, acc[4]); acc[5] = fmaf(wb.y, hj, acc[5]);
          acc[6] = fmaf(wb.z, hj, acc[6]); acc[7] = fmaf(wb.w, hj, acc[7]);
          wa = na; wb = nb;
        }
#pragma unroll
        for (int u = 0; u < 8; ++u) {
          int r = rb + u;
          if (r < GDIM) xdst[(size_t)lane * RPAD + r] = acc[u] + BVl[r];
        }
      }
      __syncthreads();
      if (tid == 0) arel(&F_XWRDY(F, li, c), 1);
    }
  }
}

// ---------------- launch ----------------
extern "C" void kernel_launch(void* const* d_in, const int* in_sizes, int n_in,
                              void* d_out, int out_size, void* d_ws, size_t ws_size,
                              hipStream_t stream) {
  const float* x    = (const float*)d_in[0];
  const float* Wih0 = (const float*)d_in[1];
  const float* Whh0 = (const float*)d_in[2];
  const float* bih0 = (const float*)d_in[3];
  const float* bhh0 = (const float*)d_in[4];
  const float* Wih1 = (const float*)d_in[5];
  const float* Whh1 = (const float*)d_in[6];
  const float* bih1 = (const float*)d_in[7];
  const float* bhh1 = (const float*)d_in[8];
  const float* Wih2 = (const float*)d_in[9];
  const float* Whh2 = (const float*)d_in[10];
  const float* bih2 = (const float*)d_in[11];
  const float* bhh2 = (const float*)d_in[12];
  const float* Wl   = (const float*)d_in[13];
  const float* bl   = (const float*)d_in[14];
  const int T = in_sizes[0];

  char* ws = (char*)d_ws;
  int*   F   = (int*)ws;                                        // 4096 B flags
  float* WT  = (float*)(ws + 4096);                             // 2,048,000 B
  float* BV  = (float*)(ws + 4096 + 2048000);                   // 8,192 B
  float* hR  = (float*)(ws + 4096 + 2048000 + 8192);            // 512,000 B
  float* xwR = (float*)(ws + 4096 + 2048000 + 8192 + 512000);   // 2,097,152 B

  hipMemsetAsync(F, 0, 4096, stream);  // reset protocol state every call/replay
  lstm_init<<<256, 256, 0, stream>>>(Wih1, bih1, bhh1, Wih2, bih2, bhh2, WT, BV);
  hipFuncSetAttribute(reinterpret_cast<const void*>(lstm_main),
                      hipFuncAttributeMaxDynamicSharedMemorySize, SMEM_BYTES);
  lstm_main<<<3 + 2 * PP, 512, SMEM_BYTES, stream>>>(
      x, Wih0, bih0, bhh0, Whh0, Whh1, Whh2, Wl, bl, F, WT, BV, hR, xwR,
      (float*)d_out, T);
}